// Round 1
// baseline (2349.228 us; speedup 1.0000x reference)
//
#include <hip/hip_runtime.h>
#include <math.h>

// LSTM persistent kernel, R16: replace the 16x16x32 MFMA GEMV with a
// v_dot2_f32_f16 VALU GEMV.
//
// Why: per-SIMD per-step the MFMA pipe was occupied 512cy (32 MFMAs x 16cy)
// for a GEMV whose 16 output columns are identical broadcasts -- 16x wasted
// MACs, and 512cy is a floor for ANY N=16 MFMA shape. v_dot2_f32_f16 is
// full-rate (2 f16 MAC/lane/instr): 512 threads x 1 W_hh row x 64 dot2
// = 256cy/SIMD/step with ZERO redundancy, f32 accumulation.
//
// Thread t owns row 128*(t&3) + (t>>2): gate g = t&3, element el = t>>2.
// Weights pre-scaled by Mk(g) (the -L2E / 2*L2E exp2 trick) live in 64
// VGPRs. h (128 f16) is broadcast-read from LDS (16x ds_read_b128, all
// lanes same address). 8 interleaved dot chains give ILP. Tail is
// gate-parallel: each lane does ONE rcp(1+exp2(z)); three quad_perm DPP
// exchanges gather the 4 gate activations; the g==0 lane owns c, does
// tanh, writes h. One barrier/step as before.
//
// Prediction: wall/step 990cy -> ~550-650cy => ~950-1200us.
// MfmaUtil -> 0, VALUBusy (reported) up to ~18-25%.
constexpr int Hdim = 128;
constexpr int TMAX = 4096;

typedef _Float16 v2h __attribute__((ext_vector_type(2)));
typedef _Float16 v8h __attribute__((ext_vector_type(8)));

#if __has_builtin(__builtin_amdgcn_exp2f)
__device__ __forceinline__ float exp2_fast(float x) {
  return __builtin_amdgcn_exp2f(x);
}
#else
__device__ __forceinline__ float exp2_fast(float x) {
  return __expf(x * 0.6931471805599453f);
}
#endif

__device__ __forceinline__ float rcp_fast(float x) {
  return __builtin_amdgcn_rcpf(x);
}

__device__ __forceinline__ float dot2f(v2h a, v2h b, float c) {
#if __has_builtin(__builtin_amdgcn_fdot2)
  return __builtin_amdgcn_fdot2(a, b, c, false);
#else
  return fmaf((float)a[0], (float)b[0], fmaf((float)a[1], (float)b[1], c));
#endif
}

// Quad-lane permute via DPP quad_perm (pure VALU, no LDS latency).
// CTRL = q0 | q1<<2 | q2<<4 | q3<<6.
template <int CTRL>
__device__ __forceinline__ float qperm(float v) {
#if __has_builtin(__builtin_amdgcn_update_dpp)
  return __int_as_float(
      __builtin_amdgcn_update_dpp(0, __float_as_int(v), CTRL, 0xF, 0xF, true));
#else
  const int x = (CTRL == 0xB1) ? 1 : (CTRL == 0x4E ? 2 : 3);
  return __shfl_xor(v, x, 64);
#endif
}

__global__ __launch_bounds__(512, 2) void lstm_dot(
    const float* __restrict__ data, const float* __restrict__ h0,
    const float* __restrict__ c0, const float* __restrict__ W_ih,
    const float* __restrict__ W_hh, const float* __restrict__ b_ih,
    const float* __restrict__ b_hh, const float* __restrict__ W_out,
    const float* __restrict__ b_out, float* __restrict__ out, int T) {
  __shared__ __align__(16) float xs[TMAX];
  __shared__ __align__(16) _Float16 hbuf[2][Hdim];

  const int b = blockIdx.x;
  const int tid = threadIdx.x;
  const int g = tid & 3;    // gate (i,f,g,o)
  const int el = tid >> 2;  // h element 0..127
  const int row = 128 * g + el;

  // Stage input row (coalesced float4).
  {
    const float4* src = (const float4*)(data + (size_t)b * T);
    float4* dst = (float4*)xs;
    for (int i = tid; i < T / 4; i += 512) dst[i] = src[i];
  }

  constexpr float L2E = 1.44269504088896f;
  const float Mr = (g == 2) ? 2.0f * L2E : -L2E;

  // My W_hh row, Mk-scaled, as 64 f16 pairs in VGPRs.
  v2h wp[64];
  {
    const float* wr = W_hh + (size_t)row * Hdim;
#pragma unroll
    for (int i = 0; i < 32; ++i) {
      float4 v = ((const float4*)wr)[i];
      wp[2 * i] = v2h{(_Float16)(Mr * v.x), (_Float16)(Mr * v.y)};
      wp[2 * i + 1] = v2h{(_Float16)(Mr * v.z), (_Float16)(Mr * v.w)};
    }
  }

  const float bias_s = Mr * (b_ih[row] + b_hh[row]);  // seeds chain a0
  const float wih_s = Mr * W_ih[row];

  float cst = c0[(size_t)b * Hdim + el];  // canonical only in g==0 lanes
  if (tid < 128) hbuf[0][tid] = (_Float16)h0[(size_t)b * Hdim + tid];
  __syncthreads();

  for (int t0 = 0; t0 < T; t0 += 4) {
    const float4 xv = *(const float4*)&xs[t0];  // 4 steps of x, one read
    const float xts[4] = {xv.x, xv.y, xv.z, xv.w};
#pragma unroll
    for (int u = 0; u < 4; ++u) {
      const int t = t0 + u;
      const _Float16* hb = hbuf[t & 1];
      _Float16* hn = hbuf[(t + 1) & 1];

      // Broadcast-read full h into registers (all lanes same address).
      v8h hv[16];
#pragma unroll
      for (int i = 0; i < 16; ++i) hv[i] = *(const v8h*)(hb + 8 * i);

      // 64 dot2 over 8 interleaved chains (ILP; pairwise-combined for
      // rounding comparable to the MFMA version).
      float a0 = bias_s, a1 = 0.f, a2 = 0.f, a3 = 0.f, a4 = 0.f, a5 = 0.f,
            a6 = 0.f, a7 = 0.f;
#pragma unroll
      for (int i = 0; i < 8; ++i) {
        const v8h hA = hv[2 * i];
        const v8h hB = hv[2 * i + 1];
        a0 = dot2f(wp[8 * i + 0], v2h{hA[0], hA[1]}, a0);
        a1 = dot2f(wp[8 * i + 1], v2h{hA[2], hA[3]}, a1);
        a2 = dot2f(wp[8 * i + 2], v2h{hA[4], hA[5]}, a2);
        a3 = dot2f(wp[8 * i + 3], v2h{hA[6], hA[7]}, a3);
        a4 = dot2f(wp[8 * i + 4], v2h{hB[0], hB[1]}, a4);
        a5 = dot2f(wp[8 * i + 5], v2h{hB[2], hB[3]}, a5);
        a6 = dot2f(wp[8 * i + 6], v2h{hB[4], hB[5]}, a6);
        a7 = dot2f(wp[8 * i + 7], v2h{hB[6], hB[7]}, a7);
      }
      const float dsum = ((a0 + a1) + (a2 + a3)) + ((a4 + a5) + (a6 + a7));

      // My gate's pre-activation (x term + bias already Mk-scaled).
      const float z = fmaf(xts[u], wih_s, dsum);
      // One transcendental pair per lane: u = 1/(1+exp2(z)).
      // g in {0,1,3}: u = sigmoid(raw). g==2: tanh(raw) = 1 - 2u.
      const float uu = rcp_fast(1.0f + exp2_fast(z));

      // Gather quad: lane g==0 sees x1=u_f, x2=u_g, x3=u_o.
      const float x1 = qperm<0xB1>(uu);  // xor 1
      const float x2 = qperm<0x4E>(uu);  // xor 2
      const float x3 = qperm<0x1B>(uu);  // xor 3

      if (g == 0) {
        const float gg = fmaf(-2.0f, x2, 1.0f);  // tanh(raw_g)
        cst = fmaf(x1, cst, uu * gg);            // c = f*c + i*g
        const float th = fmaf(
            -2.0f, rcp_fast(1.0f + exp2_fast(cst * (2.0f * L2E))), 1.0f);
        hn[el] = (_Float16)(x3 * th);  // h = o * tanh(c)
      }
      __syncthreads();
    }
  }

  // Final linear: out[b] = h_T . W_out + b_out (wave 0).
  if (tid < 64) {
    const _Float16* hf = hbuf[T & 1];
    float sum =
        (float)hf[tid] * W_out[tid] + (float)hf[tid + 64] * W_out[tid + 64];
#pragma unroll
    for (int off = 32; off > 0; off >>= 1) sum += __shfl_down(sum, off, 64);
    if (tid == 0) out[b] = sum + b_out[0];
  }
}

extern "C" void kernel_launch(void* const* d_in, const int* in_sizes, int n_in,
                              void* d_out, int out_size, void* d_ws,
                              size_t ws_size, hipStream_t stream) {
  const float* data = (const float*)d_in[0];
  const float* h0 = (const float*)d_in[1];
  const float* c0 = (const float*)d_in[2];
  const float* W_ih = (const float*)d_in[3];
  const float* W_hh = (const float*)d_in[4];
  const float* b_ih = (const float*)d_in[5];
  const float* b_hh = (const float*)d_in[6];
  const float* W_out = (const float*)d_in[7];
  const float* b_out = (const float*)d_in[8];
  float* out = (float*)d_out;

  const int B = in_sizes[1] / Hdim;  // 64
  const int T = in_sizes[0] / B;     // 4096

  lstm_dot<<<B, 512, 0, stream>>>(data, h0, c0, W_ih, W_hh, b_ih, b_hh, W_out,
                                  b_out, out, T);
}

// Round 2
// 2056.125 us; speedup vs baseline: 1.1426x; 1.1426x over previous
//
#include <hip/hip_runtime.h>
#include <math.h>

// LSTM persistent kernel, R17: wave-specialized hybrid GEMV.
//
// Model (R15+R16 measured): wall/step = GEMV issue cy/SIMD + ~500cy fixed
// (h LDS turnaround + serial activation chain + barrier). R15: 512cy MFMA
// issue (16x column waste, unavoidable at N=16). R16: dot2 path should be
// 256cy but measured ~815 -- v8h f16-element extraction forced v_pack VALU
// ops. Fix both at once:
//   waves 0-3: elements 0..63 via MFMA, exact R15 code (256cy matrix/SIMD)
//   waves 4-7: elements 64..127 via v_dot2_f32_f16, one W_hh row per lane,
//              f16 pairs moved as uint bit-casts of ds_read_b128 components
//              (sub-register selects, ZERO pack VALU) (~128cy VALU/SIMD)
// Each SIMD hosts one wave of each role; m114: MFMA wave + VALU wave on one
// CU overlap fully (time = max, not sum). Predicted step ~750cy -> ~1.25ms.
constexpr int Hdim = 128;
constexpr int TMAX = 4096;

typedef _Float16 v2h __attribute__((ext_vector_type(2)));
typedef _Float16 v8h __attribute__((ext_vector_type(8)));
typedef float v4f __attribute__((ext_vector_type(4)));

#if __has_builtin(__builtin_amdgcn_exp2f)
__device__ __forceinline__ float exp2_fast(float x) {
  return __builtin_amdgcn_exp2f(x);
}
#else
__device__ __forceinline__ float exp2_fast(float x) {
  return __expf(x * 0.6931471805599453f);
}
#endif

__device__ __forceinline__ float rcp_fast(float x) {
  return __builtin_amdgcn_rcpf(x);
}

// f32 <- dot2(f16x2, f16x2) + f32, operands carried as uint (bit-cast only,
// never element-extracted -- guarantees no pack VALU).
__device__ __forceinline__ float dot2u(unsigned a, unsigned b, float c) {
#if __has_builtin(__builtin_amdgcn_fdot2)
  return __builtin_amdgcn_fdot2(__builtin_bit_cast(v2h, a),
                                __builtin_bit_cast(v2h, b), c, false);
#else
  const v2h x = __builtin_bit_cast(v2h, a);
  const v2h y = __builtin_bit_cast(v2h, b);
  return fmaf((float)x[0], (float)y[0], fmaf((float)x[1], (float)y[1], c));
#endif
}

__device__ __forceinline__ float sel4(v4f d, int r) {
  const float s01 = (r & 1) ? d.y : d.x;
  const float s23 = (r & 1) ? d.w : d.z;
  return (r & 2) ? s23 : s01;
}

// Quad-lane permute via DPP quad_perm (pure VALU, no LDS latency).
template <int CTRL>
__device__ __forceinline__ float qperm(float v) {
#if __has_builtin(__builtin_amdgcn_update_dpp)
  return __int_as_float(
      __builtin_amdgcn_update_dpp(0, __float_as_int(v), CTRL, 0xF, 0xF, true));
#else
  const int x = (CTRL == 0xB1) ? 1 : (CTRL == 0x4E ? 2 : 3);
  return __shfl_xor(v, x, 64);
#endif
}

__global__ __launch_bounds__(512) void lstm_hyb(
    const float* __restrict__ data, const float* __restrict__ h0,
    const float* __restrict__ c0, const float* __restrict__ W_ih,
    const float* __restrict__ W_hh, const float* __restrict__ b_ih,
    const float* __restrict__ b_hh, const float* __restrict__ W_out,
    const float* __restrict__ b_out, float* __restrict__ out, int T) {
  __shared__ __align__(16) float xs[TMAX];
  __shared__ __align__(16) _Float16 hbuf[2][Hdim];

  const int b = blockIdx.x;
  const int tid = threadIdx.x;
  const int lane = tid & 63;
  const int wv = tid >> 6;
  const bool mrole = (wv < 4);  // waves 0-3: MFMA role; 4-7: dot2 role

  // Stage input row (coalesced float4).
  {
    const float4* src = (const float4*)(data + (size_t)b * T);
    float4* dst = (float4*)xs;
    for (int i = tid; i < T / 4; i += 512) dst[i] = src[i];
  }

  constexpr float L2E = 1.44269504088896f;

  // ---- MFMA-role state (els 16wv..16wv+15, wv=0..3) ----
  v8h a[4][4];
  v4f acc_init[4];
  float wihm[4];
  int p = 0, m = 0, r = 0;
  // ---- dot2-role state (els 64+16(wv-4)+local) ----
  unsigned wq[64];
  float bias_s = 0.f, wih_s = 0.f;
  int g = 0;

  int el;
  if (mrole) {
    p = lane >> 4;
    m = lane & 15;
    r = m & 3;
    el = 16 * wv + 4 * p + r;
#pragma unroll
    for (int gg = 0; gg < 4; ++gg) {
      const int row = 128 * gg + 16 * wv + m;
      const float Mr = (gg == 2) ? 2.0f * L2E : -L2E;
      const float* wr = W_hh + (size_t)row * Hdim + 8 * p;
#pragma unroll
      for (int c = 0; c < 4; ++c) {
        float4 v0 = ((const float4*)(wr + 32 * c))[0];
        float4 v1 = ((const float4*)(wr + 32 * c))[1];
        a[gg][c] = v8h{(_Float16)(Mr * v0.x), (_Float16)(Mr * v0.y),
                       (_Float16)(Mr * v0.z), (_Float16)(Mr * v0.w),
                       (_Float16)(Mr * v1.x), (_Float16)(Mr * v1.y),
                       (_Float16)(Mr * v1.z), (_Float16)(Mr * v1.w)};
      }
    }
#pragma unroll
    for (int gg = 0; gg < 4; ++gg) {
      const float Mr = (gg == 2) ? 2.0f * L2E : -L2E;
      const int row = 128 * gg + 16 * wv + 4 * p;
      acc_init[gg] = v4f{Mr * (b_ih[row + 0] + b_hh[row + 0]),
                         Mr * (b_ih[row + 1] + b_hh[row + 1]),
                         Mr * (b_ih[row + 2] + b_hh[row + 2]),
                         Mr * (b_ih[row + 3] + b_hh[row + 3])};
      wihm[gg] = Mr * W_ih[128 * gg + el];
    }
  } else {
    const int s = wv - 4;
    g = lane & 3;                  // gate i,f,g,o
    const int local = lane >> 2;   // 0..15
    el = 64 + 16 * s + local;
    const int row = 128 * g + el;
    const float Mr = (g == 2) ? 2.0f * L2E : -L2E;
    const float* wr = W_hh + (size_t)row * Hdim;
#pragma unroll
    for (int i = 0; i < 32; ++i) {
      float4 v = ((const float4*)wr)[i];
      const v2h p0{(_Float16)(Mr * v.x), (_Float16)(Mr * v.y)};
      const v2h p1{(_Float16)(Mr * v.z), (_Float16)(Mr * v.w)};
      wq[2 * i] = __builtin_bit_cast(unsigned, p0);
      wq[2 * i + 1] = __builtin_bit_cast(unsigned, p1);
    }
    bias_s = Mr * (b_ih[row] + b_hh[row]);
    wih_s = Mr * W_ih[row];
  }

  float cst = c0[(size_t)b * Hdim + el];
  if (tid < 128) hbuf[0][tid] = (_Float16)h0[(size_t)b * Hdim + tid];
  __syncthreads();

  for (int t0 = 0; t0 < T; t0 += 4) {
    const float4 xv = *(const float4*)&xs[t0];
    const float xts[4] = {xv.x, xv.y, xv.z, xv.w};
#pragma unroll
    for (int u = 0; u < 4; ++u) {
      const int t = t0 + u;
      const _Float16* hb = hbuf[t & 1];
      _Float16* hn = hbuf[(t + 1) & 1];
      const float xt = xts[u];

      if (mrole) {
        // ---- MFMA path: exact R15 inner body ----
        v8h bq[4];
#pragma unroll
        for (int c = 0; c < 4; ++c) bq[c] = *(const v8h*)(hb + 32 * c + 8 * p);

        v4f d0 = __builtin_amdgcn_mfma_f32_16x16x32_f16(a[0][0], bq[0],
                                                        acc_init[0], 0, 0, 0);
        v4f d1 = __builtin_amdgcn_mfma_f32_16x16x32_f16(a[1][0], bq[0],
                                                        acc_init[1], 0, 0, 0);
        v4f d2 = __builtin_amdgcn_mfma_f32_16x16x32_f16(a[2][0], bq[0],
                                                        acc_init[2], 0, 0, 0);
        v4f d3 = __builtin_amdgcn_mfma_f32_16x16x32_f16(a[3][0], bq[0],
                                                        acc_init[3], 0, 0, 0);
#pragma unroll
        for (int c = 1; c < 4; ++c) {
          d0 = __builtin_amdgcn_mfma_f32_16x16x32_f16(a[0][c], bq[c], d0, 0, 0, 0);
          d1 = __builtin_amdgcn_mfma_f32_16x16x32_f16(a[1][c], bq[c], d1, 0, 0, 0);
          d2 = __builtin_amdgcn_mfma_f32_16x16x32_f16(a[2][c], bq[c], d2, 0, 0, 0);
          d3 = __builtin_amdgcn_mfma_f32_16x16x32_f16(a[3][c], bq[c], d3, 0, 0, 0);
        }

        const float zi = sel4(d0, r);
        const float zf = sel4(d1, r);
        const float zg = sel4(d2, r);
        const float zo = sel4(d3, r);

        const float yi =
            rcp_fast(1.0f + exp2_fast(fmaf(xt, wihm[0], zi)));
        const float yf =
            rcp_fast(1.0f + exp2_fast(fmaf(xt, wihm[1], zf)));
        const float yg =
            fmaf(-2.0f, rcp_fast(1.0f + exp2_fast(fmaf(xt, wihm[2], zg))), 1.0f);
        const float yo =
            rcp_fast(1.0f + exp2_fast(fmaf(xt, wihm[3], zo)));

        cst = fmaf(yf, cst, yi * yg);
        const float th = fmaf(
            -2.0f, rcp_fast(1.0f + exp2_fast(cst * (2.0f * L2E))), 1.0f);
        const float h = yo * th;
        if (m < 4) hn[el] = (_Float16)h;
      } else {
        // ---- dot2 path: uint-carried f16 pairs, no packing ----
        const uint4* hp = (const uint4*)hb;
        uint4 hq[16];
#pragma unroll
        for (int i = 0; i < 16; ++i) hq[i] = hp[i];

        float a0 = bias_s, a1 = 0.f, a2 = 0.f, a3 = 0.f, a4 = 0.f, a5 = 0.f,
              a6 = 0.f, a7 = 0.f;
#pragma unroll
        for (int i = 0; i < 8; ++i) {
          const uint4 hA = hq[2 * i];
          const uint4 hB = hq[2 * i + 1];
          a0 = dot2u(wq[8 * i + 0], hA.x, a0);
          a1 = dot2u(wq[8 * i + 1], hA.y, a1);
          a2 = dot2u(wq[8 * i + 2], hA.z, a2);
          a3 = dot2u(wq[8 * i + 3], hA.w, a3);
          a4 = dot2u(wq[8 * i + 4], hB.x, a4);
          a5 = dot2u(wq[8 * i + 5], hB.y, a5);
          a6 = dot2u(wq[8 * i + 6], hB.z, a6);
          a7 = dot2u(wq[8 * i + 7], hB.w, a7);
        }
        const float dsum = ((a0 + a1) + (a2 + a3)) + ((a4 + a5) + (a6 + a7));

        const float z = fmaf(xt, wih_s, dsum);
        const float uu = rcp_fast(1.0f + exp2_fast(z));

        const float x1 = qperm<0xB1>(uu);  // gate f
        const float x2 = qperm<0x4E>(uu);  // gate g
        const float x3 = qperm<0x1B>(uu);  // gate o

        if (g == 0) {
          const float gg = fmaf(-2.0f, x2, 1.0f);  // tanh(raw_g)
          cst = fmaf(x1, cst, uu * gg);            // c = f*c + i*g
          const float th = fmaf(
              -2.0f, rcp_fast(1.0f + exp2_fast(cst * (2.0f * L2E))), 1.0f);
          hn[el] = (_Float16)(x3 * th);  // h = o * tanh(c)
        }
      }
      __syncthreads();
    }
  }

  // Final linear: out[b] = h_T . W_out + b_out (wave 0).
  if (tid < 64) {
    const _Float16* hf = hbuf[T & 1];
    float sum =
        (float)hf[tid] * W_out[tid] + (float)hf[tid + 64] * W_out[tid + 64];
#pragma unroll
    for (int off = 32; off > 0; off >>= 1) sum += __shfl_down(sum, off, 64);
    if (tid == 0) out[b] = sum + b_out[0];
  }
}

extern "C" void kernel_launch(void* const* d_in, const int* in_sizes, int n_in,
                              void* d_out, int out_size, void* d_ws,
                              size_t ws_size, hipStream_t stream) {
  const float* data = (const float*)d_in[0];
  const float* h0 = (const float*)d_in[1];
  const float* c0 = (const float*)d_in[2];
  const float* W_ih = (const float*)d_in[3];
  const float* W_hh = (const float*)d_in[4];
  const float* b_ih = (const float*)d_in[5];
  const float* b_hh = (const float*)d_in[6];
  const float* W_out = (const float*)d_in[7];
  const float* b_out = (const float*)d_in[8];
  float* out = (float*)d_out;

  const int B = in_sizes[1] / Hdim;  // 64
  const int T = in_sizes[0] / B;     // 4096

  lstm_hyb<<<B, 512, 0, stream>>>(data, h0, c0, W_ih, W_hh, b_ih, b_hh, W_out,
                                  b_out, out, T);
}